// Round 21
// baseline (300.041 us; speedup 1.0000x reference)
//
#include <hip/hip_runtime.h>
#include <hip/hip_bf16.h>
#include <float.h>

#define NPTS 8192
#define KNB  16
#define CINC 64
#define MIDC 64
#define EPSBN 1e-5f

typedef unsigned short u16;
typedef u16   us8   __attribute__((ext_vector_type(8)));
typedef __bf16 bf16x8 __attribute__((ext_vector_type(8)));
typedef float  f32x4  __attribute__((ext_vector_type(4)));

__device__ __forceinline__ float selu_f(float x) {
    const float sc = 1.0507009873554805f;
    const float al = 1.6732632423543772f;
    return x > 0.f ? sc * x : sc * al * expm1f(x);
}
__device__ __forceinline__ float bn_f(float v, const float* __restrict__ bnp, int C, int c) {
    float g = bnp[c], b = bnp[C + c], mu = bnp[2 * C + c], va = bnp[3 * C + c];
    return (v - mu) * (1.0f / sqrtf(va + EPSBN)) * g + b;
}
__device__ __forceinline__ u16 f2bf(float v) {
    __hip_bfloat16 h = __float2bfloat16(v);   // RNE
    return *reinterpret_cast<u16*>(&h);
}

__device__ __forceinline__ unsigned long long wavemin_u64(unsigned long long h) {
#pragma unroll
    for (int s = 32; s >= 1; s >>= 1) {
        const unsigned int ohi = __shfl_xor((unsigned int)(h >> 32), s);
        const unsigned int olo = __shfl_xor((unsigned int)(h & 0xFFFFFFFFu), s);
        const unsigned long long o = ((unsigned long long)ohi << 32) | olo;
        if (o < h) h = o;
    }
    return h;
}

// ---- KNN: two-pass exact-threshold (proven structure). SINGLE DELTA vs R20:
//      pass A tracks the TWO smallest u64 keys per lane; T = 16th smallest of
//      the 128 values. The 16 extracted are 16 distinct candidates (keys
//      unique) => global-16th <= T => nk<=T remains a superset filter, but T
//      is tighter (fewer pass-B insert firings). Pass B insert/merge VERBATIM
//      proven text -> output bit-identical.
__global__ __launch_bounds__(256) void knn_kernel(const float* __restrict__ p,
                                                  const float* __restrict__ q,
                                                  int* __restrict__ idx_out,
                                                  float* __restrict__ phat) {
    const int w = threadIdx.x >> 6, lane = threadIdx.x & 63;
    const int bm = blockIdx.x * 4 + w;
    const int b = bm >> 11;
    const float qx = q[bm * 3 + 0], qy = q[bm * 3 + 1], qz = q[bm * 3 + 2];
    const float qq = __fadd_rn(__fadd_rn(__fmul_rn(qx, qx), __fmul_rn(qy, qy)), __fmul_rn(qz, qz));
    const float* px = p + (size_t)b * 3 * NPTS;
    const float* py = px + NPTS;
    const float* pz = py + NPTS;

    // ---- Pass A: per-lane two smallest u64 keys (mn1 <= mn2) ----
    unsigned long long mn1 = ~0ull, mn2 = ~0ull;
#pragma unroll 2
    for (int j = 0; j < NPTS / 64; ++j) {
        const int n = lane + j * 64;
        const float ax = px[n], ay = py[n], az = pz[n];
        const float pp = __fadd_rn(__fadd_rn(__fmul_rn(ax, ax), __fmul_rn(ay, ay)), __fmul_rn(az, az));
        const float dt = __fmaf_rn(az, qz, __fmaf_rn(ay, qy, __fmul_rn(ax, qx)));
        const float d2 = __fsub_rn(__fadd_rn(qq, pp), __fmul_rn(2.0f, dt));
        const unsigned int bits = __float_as_uint(d2);
        const unsigned int key = bits ^ ((unsigned int)((int)bits >> 31) | 0x80000000u);
        const unsigned long long nk = ((unsigned long long)key << 32) | (unsigned int)n;
        if (nk < mn2) {
            const bool lt1 = nk < mn1;
            mn2 = lt1 ? mn1 : nk;
            mn1 = lt1 ? nk : mn1;
        }
    }
    // T = 16th smallest of the 128 {mn1,mn2} values (wave-uniform).
    unsigned long long T;
    {
        unsigned long long a = mn1, b2 = mn2;   // a <= b2, a = lane's current head
        for (int r = 0; r < 16; ++r) {
            const unsigned long long h = wavemin_u64(a);
            if (r == 15) T = h;
            if (a == h) { a = b2; b2 = ~0ull; }  // unique keys -> one owner pops
        }
    }

    // ---- Pass B: guarded insert, wave-level skip on nk<=T (VERBATIM proven) ----
    unsigned long long K[16];
#pragma unroll
    for (int i = 0; i < 16; ++i) K[i] = ~0ull;

#pragma unroll 2
    for (int j = 0; j < NPTS / 64; ++j) {
        const int n = lane + j * 64;
        const float ax = px[n], ay = py[n], az = pz[n];
        const float pp = __fadd_rn(__fadd_rn(__fmul_rn(ax, ax), __fmul_rn(ay, ay)), __fmul_rn(az, az));
        const float dt = __fmaf_rn(az, qz, __fmaf_rn(ay, qy, __fmul_rn(ax, qx)));
        const float d2 = __fsub_rn(__fadd_rn(qq, pp), __fmul_rn(2.0f, dt));
        const unsigned int bits = __float_as_uint(d2);
        const unsigned int key = bits ^ ((unsigned int)((int)bits >> 31) | 0x80000000u);
        const unsigned long long nk = ((unsigned long long)key << 32) | (unsigned int)n;
        if (__any(nk <= T)) {
            if (nk <= T && nk < K[15]) {
                bool c[16];
#pragma unroll
                for (int i = 0; i < 16; ++i) c[i] = nk < K[i];
#pragma unroll
                for (int i = 15; i >= 1; --i) K[i] = c[i] ? (c[i - 1] ? K[i - 1] : nk) : K[i];
                K[0] = c[0] ? nk : K[0];
            }
        }
    }

    unsigned long long win_i = 0, win_p = 0;
    for (int r = 0; r < 16; ++r) {
        const unsigned long long h = wavemin_u64(K[0]);
        const bool own = (K[0] == h);
#pragma unroll
        for (int i = 0; i < 15; ++i) K[i] = own ? K[i + 1] : K[i];
        K[15] = own ? ~0ull : K[15];
        if (r == lane) win_i = h;
        if (lane < 48 && r == (lane / 3)) win_p = h;
    }
    if (lane < 16) idx_out[bm * 16 + lane] = (int)(win_i & 0xFFFFFFFFu);
    if (lane < 48) {
        const int kk = lane / 3, c = lane - kk * 3;
        const int n = (int)(win_p & 0xFFFFFFFFu);
        phat[(size_t)bm * 48 + lane] = p[((size_t)b * 3 + c) * NPTS + n] - q[bm * 3 + c];
    }
}

// ---- xT[b][n][c] = x[b][c][n], LDS-tiled (coalesced read AND write) ----
__global__ __launch_bounds__(256) void transpose_x_kernel(const float* __restrict__ x,
                                                          float* __restrict__ xT) {
    __shared__ float tile[64][65];
    const int b = blockIdx.y;
    const int n0 = blockIdx.x * 64;
    const int t = threadIdx.x;
    const int tn = t & 63, tq = t >> 6;    // tq in 0..3
#pragma unroll
    for (int i = 0; i < 16; ++i) {
        const int c = tq * 16 + i;
        tile[c][tn] = x[((size_t)b * 64 + c) * NPTS + n0 + tn];
    }
    __syncthreads();
#pragma unroll
    for (int i = 0; i < 16; ++i) {
        const int n = tq * 16 + i;
        xT[((size_t)b * NPTS + n0 + n) * 64 + tn] = tile[tn][n];
    }
}

// ---------------- fused gather + mlp1 (h1,h2) -> XHAT (R20-passing) ----------------
__global__ __launch_bounds__(256) void mlp1_kernel(const float* __restrict__ xT,
                                                   const float* __restrict__ w1,
                                                   const float* __restrict__ bn1,
                                                   const float* __restrict__ w2,
                                                   const float* __restrict__ bn2,
                                                   const int* __restrict__ idxb,
                                                   const float* __restrict__ phat,
                                                   float* __restrict__ xhat) {
    __shared__ float ph[48];
    __shared__ float h1[16 * 64];
    __shared__ float4 w2s4[16][64];   // [dq][e]
    __shared__ int idxs[16];
    const int bm = blockIdx.x;
    const int b = bm >> 11;
    const int t = threadIdx.x;
    if (t < 48) ph[t] = phat[(size_t)bm * 48 + t];
    if (t < 16) idxs[t] = idxb[bm * 16 + t];
#pragma unroll
    for (int i = 0; i < 4; ++i) {
        const int fi = t + i * 256;           // float4 index into w2 (1024 float4s)
        const int e = fi >> 4, dq = fi & 15;
        w2s4[dq][e] = ((const float4*)w2)[fi];
    }
    __syncthreads();
#pragma unroll
    for (int i = 0; i < 4; ++i) {
        const int o = t + i * 256;
        const int kk = o >> 6, d = o & 63;
        float s = ph[kk * 3 + 0] * w1[d * 3 + 0] + ph[kk * 3 + 1] * w1[d * 3 + 1] + ph[kk * 3 + 2] * w1[d * 3 + 2];
        h1[kk * 64 + d] = selu_f(bn_f(s, bn1, MIDC, d));
    }
    __syncthreads();
#pragma unroll
    for (int i = 0; i < 4; ++i) {
        const int o = t + i * 256;
        const int kk = o >> 6, e = o & 63;
        const float4* h4 = (const float4*)&h1[kk * 64];
        float s = 0.f;
#pragma unroll
        for (int dq = 0; dq < 16; ++dq) {
            const float4 hv = h4[dq];
            const float4 wv = w2s4[dq][e];
            s += hv.x * wv.x; s += hv.y * wv.y; s += hv.z * wv.z; s += hv.w * wv.w;
        }
        xhat[(size_t)bm * 2048 + kk * 128 + e] = selu_f(bn_f(s, bn2, MIDC, e));
    }
    // coalesced gather: 256 threads = 16 kk x 16 c4, one float4 each
    {
        const int kk = t >> 4, c4 = t & 15;
        const float4 v = *(const float4*)(xT + ((size_t)b * NPTS + idxs[kk]) * 64 + c4 * 4);
        *(float4*)(xhat + (size_t)bm * 2048 + kk * 128 + 64 + c4 * 4) = v;
    }
}

// ---------------- generic tiled fp32 GEMM: C = A[M][K] x B[N][K]^T ----------------
template <int MODE>
__global__ __launch_bounds__(256) void gemm_bt(const float* __restrict__ A, int lda,
                                               const float* __restrict__ B, int ldb,
                                               float* __restrict__ C, int ldc,
                                               int Kd, const float* __restrict__ bnp, int Nc) {
    __shared__ float As[16][68];
    __shared__ float Bs[16][68];
    const int t = threadIdx.x;
    const int tx = t & 15, ty = t >> 4;
    const int row0 = blockIdx.y * 64, col0 = blockIdx.x * 64;
    const int r = t >> 2, q4 = t & 3;
    float acc[4][4] = {};
    for (int k0 = 0; k0 < Kd; k0 += 16) {
        const float4 av = *(const float4*)(A + (size_t)(row0 + r) * lda + k0 + q4 * 4);
        const float4 bv = *(const float4*)(B + (size_t)(col0 + r) * ldb + k0 + q4 * 4);
        As[q4 * 4 + 0][r] = av.x; As[q4 * 4 + 1][r] = av.y;
        As[q4 * 4 + 2][r] = av.z; As[q4 * 4 + 3][r] = av.w;
        Bs[q4 * 4 + 0][r] = bv.x; Bs[q4 * 4 + 1][r] = bv.y;
        Bs[q4 * 4 + 2][r] = bv.z; Bs[q4 * 4 + 3][r] = bv.w;
        __syncthreads();
#pragma unroll
        for (int kk = 0; kk < 16; ++kk) {
            float a0 = As[kk][ty * 4 + 0], a1 = As[kk][ty * 4 + 1];
            float a2 = As[kk][ty * 4 + 2], a3 = As[kk][ty * 4 + 3];
            float b0 = Bs[kk][tx * 4 + 0], b1 = Bs[kk][tx * 4 + 1];
            float b2 = Bs[kk][tx * 4 + 2], b3 = Bs[kk][tx * 4 + 3];
            acc[0][0] += a0 * b0; acc[0][1] += a0 * b1; acc[0][2] += a0 * b2; acc[0][3] += a0 * b3;
            acc[1][0] += a1 * b0; acc[1][1] += a1 * b1; acc[1][2] += a1 * b2; acc[1][3] += a1 * b3;
            acc[2][0] += a2 * b0; acc[2][1] += a2 * b1; acc[2][2] += a2 * b2; acc[2][3] += a2 * b3;
            acc[3][0] += a3 * b0; acc[3][1] += a3 * b1; acc[3][2] += a3 * b2; acc[3][3] += a3 * b3;
        }
        __syncthreads();
    }
#pragma unroll
    for (int i = 0; i < 4; ++i) {
#pragma unroll
        for (int j = 0; j < 4; ++j) {
            const int row = row0 + ty * 4 + i, col = col0 + tx * 4 + j;
            float v = acc[i][j];
            if (MODE >= 1) v = selu_f(bn_f(v, bnp, Nc, col));
            if (MODE == 2) {
                C[(((size_t)(row >> 11)) * Nc + col) * 2048 + (row & 2047)] = v;
            } else {
                C[(size_t)row * ldc + col] = v;
            }
        }
    }
}

// ---------------- per-m X-transform (float4 LDS, R20-passing) ----------
template <int EMIT_BF>
__global__ __launch_bounds__(256) void xtrans_kernel(float* __restrict__ xhat,
                                                     const float* __restrict__ tmat,
                                                     u16* __restrict__ xhb) {
    __shared__ float4 xs4[16][32];
    __shared__ float Tm[256];
    const int bm = blockIdx.x, t = threadIdx.x;
#pragma unroll
    for (int i = 0; i < 2; ++i) {
        const int f4 = t + i * 256;          // 0..511
        const int j = f4 >> 5, c4 = f4 & 31;
        xs4[j][c4] = ((const float4*)(xhat + (size_t)bm * 2048))[f4];
    }
    Tm[t] = tmat[(size_t)bm * 256 + t];
    __syncthreads();
    const int c4 = t & 31, kk0 = t >> 5;     // kk0 in 0..7
#pragma unroll
    for (int half = 0; half < 2; ++half) {
        const int kk = kk0 + half * 8;
        float sx = 0.f, sy = 0.f, sz = 0.f, sw = 0.f;
#pragma unroll
        for (int j = 0; j < 16; ++j) {
            const float tv = Tm[kk * 16 + j];
            const float4 xv = xs4[j][c4];
            sx += tv * xv.x; sy += tv * xv.y; sz += tv * xv.z; sw += tv * xv.w;
        }
        const size_t base = (size_t)bm * 2048 + kk * 128 + c4 * 4;
        if (EMIT_BF) {
            ushort4 o;
            o.x = f2bf(sx); o.y = f2bf(sy); o.z = f2bf(sz); o.w = f2bf(sw);
            *(ushort4*)(xhb + base) = o;
        } else {
            float4 o; o.x = sx; o.y = sy; o.z = sz; o.w = sw;
            *(float4*)(xhat + base) = o;
        }
    }
}

// ---------------- final GEMM via bf16 MFMA (R14-proven) --------
__global__ __launch_bounds__(256) void gemm_mfma_final(const u16* __restrict__ XHB,
                                                       const u16* __restrict__ WCBH,
                                                       const float* __restrict__ bno,
                                                       float* __restrict__ out1) {
    __shared__ u16 As[64][72];
    __shared__ u16 Bs[64][72];
    const int t = threadIdx.x;
    const int w = t >> 6, lane = t & 63;
    const int wm = w >> 1, wn = w & 1;
    const int row0 = blockIdx.y * 64, col0 = blockIdx.x * 64;
    const int srow = t >> 2, skq = t & 3;

    f32x4 acc[2][2] = {};

    for (int k0 = 0; k0 < 2048; k0 += 64) {
        __syncthreads();
        const u16* ga = XHB + (size_t)(row0 + srow) * 2048 + k0 + skq * 16;
        const u16* gb = WCBH + (size_t)(col0 + srow) * 2048 + k0 + skq * 16;
        *(us8*)&As[srow][skq * 16 + 0] = *(const us8*)(ga + 0);
        *(us8*)&As[srow][skq * 16 + 8] = *(const us8*)(ga + 8);
        *(us8*)&Bs[srow][skq * 16 + 0] = *(const us8*)(gb + 0);
        *(us8*)&Bs[srow][skq * 16 + 8] = *(const us8*)(gb + 8);
        __syncthreads();
#pragma unroll
        for (int ks = 0; ks < 2; ++ks) {
            const int kb = ks * 32 + (lane >> 4) * 8;
            const bf16x8 a0 = *(const bf16x8*)&As[wm * 32 + (lane & 15)][kb];
            const bf16x8 a1 = *(const bf16x8*)&As[wm * 32 + 16 + (lane & 15)][kb];
            const bf16x8 b0 = *(const bf16x8*)&Bs[wn * 32 + (lane & 15)][kb];
            const bf16x8 b1 = *(const bf16x8*)&Bs[wn * 32 + 16 + (lane & 15)][kb];
            acc[0][0] = __builtin_amdgcn_mfma_f32_16x16x32_bf16(a0, b0, acc[0][0], 0, 0, 0);
            acc[0][1] = __builtin_amdgcn_mfma_f32_16x16x32_bf16(a0, b1, acc[0][1], 0, 0, 0);
            acc[1][0] = __builtin_amdgcn_mfma_f32_16x16x32_bf16(a1, b0, acc[1][0], 0, 0, 0);
            acc[1][1] = __builtin_amdgcn_mfma_f32_16x16x32_bf16(a1, b1, acc[1][1], 0, 0, 0);
        }
    }
#pragma unroll
    for (int mi = 0; mi < 2; ++mi) {
#pragma unroll
        for (int ni = 0; ni < 2; ++ni) {
            const int col = col0 + wn * 32 + ni * 16 + (lane & 15);
            const int rowg = row0 + wm * 32 + mi * 16 + (lane >> 4) * 4;
            const int b = rowg >> 11, m = rowg & 2047;
            float4 v;
            v.x = selu_f(bn_f(acc[mi][ni][0], bno, 256, col));
            v.y = selu_f(bn_f(acc[mi][ni][1], bno, 256, col));
            v.z = selu_f(bn_f(acc[mi][ni][2], bno, 256, col));
            v.w = selu_f(bn_f(acc[mi][ni][3], bno, 256, col));
            *(float4*)(out1 + ((size_t)(b * 256 + col)) * 2048 + m) = v;
        }
    }
}

// ---------------- small prep kernels ----------------
__global__ void transpose_q_kernel(const float* __restrict__ q, float* __restrict__ out0) {
    const int t = blockIdx.x * 256 + threadIdx.x;
    if (t >= 4 * 3 * 2048) return;
    const int b = t / 6144, rem = t % 6144, c = rem >> 11, m = rem & 2047;
    out0[t] = q[((size_t)b * 2048 + m) * 3 + c];
}
__global__ void prep_wt1_kernel(const float* __restrict__ wt1, float* __restrict__ wt1r) {
    const int t = blockIdx.x * 256 + threadIdx.x;
    if (t >= 256 * 48) return;
    const int o = t / 48, rem = t % 48, kk = rem / 3, c = rem % 3;
    wt1r[t] = wt1[o * 48 + c * 16 + kk];
}
__global__ void prep_wc_kernel(const float* __restrict__ wc, float* __restrict__ wcb) {
    const int t = blockIdx.x * 256 + threadIdx.x;
    if (t >= 256 * 2048) return;
    const int o = t >> 11, f = t & 2047, kk = f >> 7, c = f & 127;
    wcb[t] = wc[o * 2048 + c * 16 + kk];
}
__global__ void prep_wcbh_kernel(const float* __restrict__ wcb, u16* __restrict__ wcbh) {
    const int t = blockIdx.x * 256 + threadIdx.x;
    if (t >= 256 * 2048) return;
    wcbh[t] = f2bf(wcb[t]);
}

extern "C" void kernel_launch(void* const* d_in, const int* in_sizes, int n_in,
                              void* d_out, int out_size, void* d_ws, size_t ws_size,
                              hipStream_t stream) {
    const float* p    = (const float*)d_in[0];
    const float* x    = (const float*)d_in[1];
    const float* q    = (const float*)d_in[2];
    const float* w1   = (const float*)d_in[3];
    const float* bn1  = (const float*)d_in[4];
    const float* w2   = (const float*)d_in[5];
    const float* bn2  = (const float*)d_in[6];
    const float* wt1  = (const float*)d_in[7];
    const float* bnt1 = (const float*)d_in[8];
    const float* wt2  = (const float*)d_in[9];
    const float* bnt2 = (const float*)d_in[10];
    const float* wt3  = (const float*)d_in[11];
    const float* wc   = (const float*)d_in[12];
    const float* bno  = (const float*)d_in[13];
    float* out = (float*)d_out;

    float* ws   = (float*)d_ws;
    float* WT1R = ws;                         // 12288 floats
    float* WCB  = WT1R + 12288;               // 524288
    int*   IDX  = (int*)(WCB + 524288);       // 131072 ints
    float* PHAT = (float*)(IDX + 131072);     // 393216
    float* BUFA = PHAT + 393216;              // 2097152
    float* BUFB = BUFA + 2097152;             // 2097152
    float* XHAT = BUFB + 2097152;             // 16777216
    u16*   XHB  = (u16*)(XHAT + 16777216);    // 16777216 u16 = 32 MB
    u16*   WCBH = XHB + 16777216;             // 524288 u16 = 1 MB
    float* XT   = BUFA;                       // ALIAS: mlp1 consumes XT before BUFA's
                                              // first write (gemm_bt<1> #1, post-mlp1)
    const size_t NEED = (22032384ull + 8388608ull + 262144ull) * 4ull;  // ~117 MB
    const bool use_mfma = (ws_size >= NEED);

    transpose_q_kernel<<<96, 256, 0, stream>>>(q, out);
    prep_wt1_kernel<<<48, 256, 0, stream>>>(wt1, WT1R);
    prep_wc_kernel<<<2048, 256, 0, stream>>>(wc, WCB);
    if (use_mfma) prep_wcbh_kernel<<<2048, 256, 0, stream>>>(WCB, WCBH);
    transpose_x_kernel<<<dim3(128, 4), 256, 0, stream>>>(x, XT);

    knn_kernel<<<2048, 256, 0, stream>>>(p, q, IDX, PHAT);
    mlp1_kernel<<<8192, 256, 0, stream>>>(XT, w1, bn1, w2, bn2, IDX, PHAT, XHAT);

    // t-path GEMMs: [8192 x 256]
    gemm_bt<1><<<dim3(4, 128), 256, 0, stream>>>(PHAT, 48, WT1R, 48, BUFA, 256, 48, bnt1, 256);
    gemm_bt<1><<<dim3(4, 128), 256, 0, stream>>>(BUFA, 256, wt2, 256, BUFB, 256, 256, bnt2, 256);
    gemm_bt<0><<<dim3(4, 128), 256, 0, stream>>>(BUFB, 256, wt3, 256, BUFA, 256, 256, nullptr, 256);

    if (use_mfma) {
        // y = T @ x_hat -> bf16 XHB directly (fp32 XHAT writeback skipped)
        xtrans_kernel<1><<<8192, 256, 0, stream>>>(XHAT, BUFA, XHB);
        gemm_mfma_final<<<dim3(4, 128), 256, 0, stream>>>(XHB, WCBH, bno, out + 24576);
    } else {
        xtrans_kernel<0><<<8192, 256, 0, stream>>>(XHAT, BUFA, nullptr);
        gemm_bt<2><<<dim3(4, 128), 256, 0, stream>>>(XHAT, 2048, WCB, 2048, out + 24576, 0, 2048, bno, 256);
    }
}

// Round 22
// 267.502 us; speedup vs baseline: 1.1216x; 1.1216x over previous
//
#include <hip/hip_runtime.h>
#include <hip/hip_bf16.h>
#include <float.h>

#define NPTS 8192
#define KNB  16
#define CINC 64
#define MIDC 64
#define EPSBN 1e-5f

typedef unsigned short u16;
typedef u16   us8   __attribute__((ext_vector_type(8)));
typedef __bf16 bf16x8 __attribute__((ext_vector_type(8)));
typedef float  f32x4  __attribute__((ext_vector_type(4)));

__device__ __forceinline__ float selu_f(float x) {
    const float sc = 1.0507009873554805f;
    const float al = 1.6732632423543772f;
    return x > 0.f ? sc * x : sc * al * expm1f(x);
}
__device__ __forceinline__ float bn_f(float v, const float* __restrict__ bnp, int C, int c) {
    float g = bnp[c], b = bnp[C + c], mu = bnp[2 * C + c], va = bnp[3 * C + c];
    return (v - mu) * (1.0f / sqrtf(va + EPSBN)) * g + b;
}
__device__ __forceinline__ u16 f2bf(float v) {
    __hip_bfloat16 h = __float2bfloat16(v);   // RNE
    return *reinterpret_cast<u16*>(&h);
}

__device__ __forceinline__ unsigned long long wavemin_u64(unsigned long long h) {
#pragma unroll
    for (int s = 32; s >= 1; s >>= 1) {
        const unsigned int ohi = __shfl_xor((unsigned int)(h >> 32), s);
        const unsigned int olo = __shfl_xor((unsigned int)(h & 0xFFFFFFFFu), s);
        const unsigned long long o = ((unsigned long long)ohi << 32) | olo;
        if (o < h) h = o;
    }
    return h;
}

// ---- KNN (R18-PASSING text, reverted from two-min): two-pass exact threshold ----
__global__ __launch_bounds__(256) void knn_kernel(const float* __restrict__ p,
                                                  const float* __restrict__ q,
                                                  int* __restrict__ idx_out,
                                                  float* __restrict__ phat) {
    const int w = threadIdx.x >> 6, lane = threadIdx.x & 63;
    const int bm = blockIdx.x * 4 + w;
    const int b = bm >> 11;
    const float qx = q[bm * 3 + 0], qy = q[bm * 3 + 1], qz = q[bm * 3 + 2];
    const float qq = __fadd_rn(__fadd_rn(__fmul_rn(qx, qx), __fmul_rn(qy, qy)), __fmul_rn(qz, qz));
    const float* px = p + (size_t)b * 3 * NPTS;
    const float* py = px + NPTS;
    const float* pz = py + NPTS;

    unsigned long long mn = ~0ull;
#pragma unroll 2
    for (int j = 0; j < NPTS / 64; ++j) {
        const int n = lane + j * 64;
        const float ax = px[n], ay = py[n], az = pz[n];
        const float pp = __fadd_rn(__fadd_rn(__fmul_rn(ax, ax), __fmul_rn(ay, ay)), __fmul_rn(az, az));
        const float dt = __fmaf_rn(az, qz, __fmaf_rn(ay, qy, __fmul_rn(ax, qx)));
        const float d2 = __fsub_rn(__fadd_rn(qq, pp), __fmul_rn(2.0f, dt));
        const unsigned int bits = __float_as_uint(d2);
        const unsigned int key = bits ^ ((unsigned int)((int)bits >> 31) | 0x80000000u);
        const unsigned long long nk = ((unsigned long long)key << 32) | (unsigned int)n;
        if (nk < mn) mn = nk;
    }
    unsigned long long T;
    {
        unsigned long long mcur = mn;
        for (int r = 0; r < 16; ++r) {
            const unsigned long long h = wavemin_u64(mcur);
            if (r == 15) T = h;
            if (mcur == h) mcur = ~0ull;
        }
    }

    unsigned long long K[16];
#pragma unroll
    for (int i = 0; i < 16; ++i) K[i] = ~0ull;

#pragma unroll 2
    for (int j = 0; j < NPTS / 64; ++j) {
        const int n = lane + j * 64;
        const float ax = px[n], ay = py[n], az = pz[n];
        const float pp = __fadd_rn(__fadd_rn(__fmul_rn(ax, ax), __fmul_rn(ay, ay)), __fmul_rn(az, az));
        const float dt = __fmaf_rn(az, qz, __fmaf_rn(ay, qy, __fmul_rn(ax, qx)));
        const float d2 = __fsub_rn(__fadd_rn(qq, pp), __fmul_rn(2.0f, dt));
        const unsigned int bits = __float_as_uint(d2);
        const unsigned int key = bits ^ ((unsigned int)((int)bits >> 31) | 0x80000000u);
        const unsigned long long nk = ((unsigned long long)key << 32) | (unsigned int)n;
        if (__any(nk <= T)) {
            if (nk <= T && nk < K[15]) {
                bool c[16];
#pragma unroll
                for (int i = 0; i < 16; ++i) c[i] = nk < K[i];
#pragma unroll
                for (int i = 15; i >= 1; --i) K[i] = c[i] ? (c[i - 1] ? K[i - 1] : nk) : K[i];
                K[0] = c[0] ? nk : K[0];
            }
        }
    }

    unsigned long long win_i = 0, win_p = 0;
    for (int r = 0; r < 16; ++r) {
        const unsigned long long h = wavemin_u64(K[0]);
        const bool own = (K[0] == h);
#pragma unroll
        for (int i = 0; i < 15; ++i) K[i] = own ? K[i + 1] : K[i];
        K[15] = own ? ~0ull : K[15];
        if (r == lane) win_i = h;
        if (lane < 48 && r == (lane / 3)) win_p = h;
    }
    if (lane < 16) idx_out[bm * 16 + lane] = (int)(win_i & 0xFFFFFFFFu);
    if (lane < 48) {
        const int kk = lane / 3, c = lane - kk * 3;
        const int n = (int)(win_p & 0xFFFFFFFFu);
        phat[(size_t)bm * 48 + lane] = p[((size_t)b * 3 + c) * NPTS + n] - q[bm * 3 + c];
    }
}

// ---- xT[b][n][c] = x[b][c][n], LDS-tiled (R20-passing) ----
__global__ __launch_bounds__(256) void transpose_x_kernel(const float* __restrict__ x,
                                                          float* __restrict__ xT) {
    __shared__ float tile[64][65];
    const int b = blockIdx.y;
    const int n0 = blockIdx.x * 64;
    const int t = threadIdx.x;
    const int tn = t & 63, tq = t >> 6;
#pragma unroll
    for (int i = 0; i < 16; ++i) {
        const int c = tq * 16 + i;
        tile[c][tn] = x[((size_t)b * 64 + c) * NPTS + n0 + tn];
    }
    __syncthreads();
#pragma unroll
    for (int i = 0; i < 16; ++i) {
        const int n = tq * 16 + i;
        xT[((size_t)b * NPTS + n0 + n) * 64 + tn] = tile[tn][n];
    }
}

// ---------------- fused gather + mlp1 (R20-passing) ----------------
__global__ __launch_bounds__(256) void mlp1_kernel(const float* __restrict__ xT,
                                                   const float* __restrict__ w1,
                                                   const float* __restrict__ bn1,
                                                   const float* __restrict__ w2,
                                                   const float* __restrict__ bn2,
                                                   const int* __restrict__ idxb,
                                                   const float* __restrict__ phat,
                                                   float* __restrict__ xhat) {
    __shared__ float ph[48];
    __shared__ float h1[16 * 64];
    __shared__ float4 w2s4[16][64];
    __shared__ int idxs[16];
    const int bm = blockIdx.x;
    const int b = bm >> 11;
    const int t = threadIdx.x;
    if (t < 48) ph[t] = phat[(size_t)bm * 48 + t];
    if (t < 16) idxs[t] = idxb[bm * 16 + t];
#pragma unroll
    for (int i = 0; i < 4; ++i) {
        const int fi = t + i * 256;
        const int e = fi >> 4, dq = fi & 15;
        w2s4[dq][e] = ((const float4*)w2)[fi];
    }
    __syncthreads();
#pragma unroll
    for (int i = 0; i < 4; ++i) {
        const int o = t + i * 256;
        const int kk = o >> 6, d = o & 63;
        float s = ph[kk * 3 + 0] * w1[d * 3 + 0] + ph[kk * 3 + 1] * w1[d * 3 + 1] + ph[kk * 3 + 2] * w1[d * 3 + 2];
        h1[kk * 64 + d] = selu_f(bn_f(s, bn1, MIDC, d));
    }
    __syncthreads();
#pragma unroll
    for (int i = 0; i < 4; ++i) {
        const int o = t + i * 256;
        const int kk = o >> 6, e = o & 63;
        const float4* h4 = (const float4*)&h1[kk * 64];
        float s = 0.f;
#pragma unroll
        for (int dq = 0; dq < 16; ++dq) {
            const float4 hv = h4[dq];
            const float4 wv = w2s4[dq][e];
            s += hv.x * wv.x; s += hv.y * wv.y; s += hv.z * wv.z; s += hv.w * wv.w;
        }
        xhat[(size_t)bm * 2048 + kk * 128 + e] = selu_f(bn_f(s, bn2, MIDC, e));
    }
    {
        const int kk = t >> 4, c4 = t & 15;
        const float4 v = *(const float4*)(xT + ((size_t)b * NPTS + idxs[kk]) * 64 + c4 * 4);
        *(float4*)(xhat + (size_t)bm * 2048 + kk * 128 + 64 + c4 * 4) = v;
    }
}

// ---------------- generic tiled fp32 GEMM: C = A[M][K] x B[N][K]^T ----------------
// MODE 0: plain fp32; 1: bn+selu fp32; 2: bn+selu transposed; 3: bn+selu -> bf16 u16
template <int MODE>
__global__ __launch_bounds__(256) void gemm_bt(const float* __restrict__ A, int lda,
                                               const float* __restrict__ B, int ldb,
                                               float* __restrict__ C, int ldc,
                                               int Kd, const float* __restrict__ bnp, int Nc) {
    __shared__ float As[16][68];
    __shared__ float Bs[16][68];
    const int t = threadIdx.x;
    const int tx = t & 15, ty = t >> 4;
    const int row0 = blockIdx.y * 64, col0 = blockIdx.x * 64;
    const int r = t >> 2, q4 = t & 3;
    float acc[4][4] = {};
    for (int k0 = 0; k0 < Kd; k0 += 16) {
        const float4 av = *(const float4*)(A + (size_t)(row0 + r) * lda + k0 + q4 * 4);
        const float4 bv = *(const float4*)(B + (size_t)(col0 + r) * ldb + k0 + q4 * 4);
        As[q4 * 4 + 0][r] = av.x; As[q4 * 4 + 1][r] = av.y;
        As[q4 * 4 + 2][r] = av.z; As[q4 * 4 + 3][r] = av.w;
        Bs[q4 * 4 + 0][r] = bv.x; Bs[q4 * 4 + 1][r] = bv.y;
        Bs[q4 * 4 + 2][r] = bv.z; Bs[q4 * 4 + 3][r] = bv.w;
        __syncthreads();
#pragma unroll
        for (int kk = 0; kk < 16; ++kk) {
            float a0 = As[kk][ty * 4 + 0], a1 = As[kk][ty * 4 + 1];
            float a2 = As[kk][ty * 4 + 2], a3 = As[kk][ty * 4 + 3];
            float b0 = Bs[kk][tx * 4 + 0], b1 = Bs[kk][tx * 4 + 1];
            float b2 = Bs[kk][tx * 4 + 2], b3 = Bs[kk][tx * 4 + 3];
            acc[0][0] += a0 * b0; acc[0][1] += a0 * b1; acc[0][2] += a0 * b2; acc[0][3] += a0 * b3;
            acc[1][0] += a1 * b0; acc[1][1] += a1 * b1; acc[1][2] += a1 * b2; acc[1][3] += a1 * b3;
            acc[2][0] += a2 * b0; acc[2][1] += a2 * b1; acc[2][2] += a2 * b2; acc[2][3] += a2 * b3;
            acc[3][0] += a3 * b0; acc[3][1] += a3 * b1; acc[3][2] += a3 * b2; acc[3][3] += a3 * b3;
        }
        __syncthreads();
    }
#pragma unroll
    for (int i = 0; i < 4; ++i) {
#pragma unroll
        for (int j = 0; j < 4; ++j) {
            const int row = row0 + ty * 4 + i, col = col0 + tx * 4 + j;
            float v = acc[i][j];
            if (MODE >= 1) v = selu_f(bn_f(v, bnp, Nc, col));
            if (MODE == 2) {
                C[(((size_t)(row >> 11)) * Nc + col) * 2048 + (row & 2047)] = v;
            } else if (MODE == 3) {
                ((u16*)C)[(size_t)row * ldc + col] = f2bf(v);
            } else {
                C[(size_t)row * ldc + col] = v;
            }
        }
    }
}

// ---- t-path GEMM via bf16 MFMA (proven gemm_mfma_final body, K parameterized).
//      STORE 0: bn+selu -> bf16 u16 row-major; STORE 1: plain fp32 row-major.
template <int STORE>
__global__ __launch_bounds__(256) void gemm_mfma_t(const u16* __restrict__ A,
                                                   const u16* __restrict__ B,
                                                   int Kd,
                                                   const float* __restrict__ bnp,
                                                   u16* __restrict__ C16,
                                                   float* __restrict__ C32) {
    __shared__ u16 As[64][72];
    __shared__ u16 Bs[64][72];
    const int t = threadIdx.x;
    const int w = t >> 6, lane = t & 63;
    const int wm = w >> 1, wn = w & 1;
    const int row0 = blockIdx.y * 64, col0 = blockIdx.x * 64;
    const int srow = t >> 2, skq = t & 3;

    f32x4 acc[2][2] = {};

    for (int k0 = 0; k0 < Kd; k0 += 64) {
        __syncthreads();
        const u16* ga = A + (size_t)(row0 + srow) * Kd + k0 + skq * 16;
        const u16* gb = B + (size_t)(col0 + srow) * Kd + k0 + skq * 16;
        *(us8*)&As[srow][skq * 16 + 0] = *(const us8*)(ga + 0);
        *(us8*)&As[srow][skq * 16 + 8] = *(const us8*)(ga + 8);
        *(us8*)&Bs[srow][skq * 16 + 0] = *(const us8*)(gb + 0);
        *(us8*)&Bs[srow][skq * 16 + 8] = *(const us8*)(gb + 8);
        __syncthreads();
#pragma unroll
        for (int ks = 0; ks < 2; ++ks) {
            const int kb = ks * 32 + (lane >> 4) * 8;
            const bf16x8 a0 = *(const bf16x8*)&As[wm * 32 + (lane & 15)][kb];
            const bf16x8 a1 = *(const bf16x8*)&As[wm * 32 + 16 + (lane & 15)][kb];
            const bf16x8 b0 = *(const bf16x8*)&Bs[wn * 32 + (lane & 15)][kb];
            const bf16x8 b1 = *(const bf16x8*)&Bs[wn * 32 + 16 + (lane & 15)][kb];
            acc[0][0] = __builtin_amdgcn_mfma_f32_16x16x32_bf16(a0, b0, acc[0][0], 0, 0, 0);
            acc[0][1] = __builtin_amdgcn_mfma_f32_16x16x32_bf16(a0, b1, acc[0][1], 0, 0, 0);
            acc[1][0] = __builtin_amdgcn_mfma_f32_16x16x32_bf16(a1, b0, acc[1][0], 0, 0, 0);
            acc[1][1] = __builtin_amdgcn_mfma_f32_16x16x32_bf16(a1, b1, acc[1][1], 0, 0, 0);
        }
    }
#pragma unroll
    for (int mi = 0; mi < 2; ++mi) {
#pragma unroll
        for (int ni = 0; ni < 2; ++ni) {
            const int col = col0 + wn * 32 + ni * 16 + (lane & 15);
            const int rowg = row0 + wm * 32 + mi * 16 + (lane >> 4) * 4;
#pragma unroll
            for (int r2 = 0; r2 < 4; ++r2) {
                float v = acc[mi][ni][r2];
                if (STORE == 0) {
                    v = selu_f(bn_f(v, bnp, 256, col));
                    C16[(size_t)(rowg + r2) * 256 + col] = f2bf(v);
                } else {
                    C32[(size_t)(rowg + r2) * 256 + col] = v;
                }
            }
        }
    }
}

// ---------------- per-m X-transform (float4 LDS, R20-passing) ----------
template <int EMIT_BF>
__global__ __launch_bounds__(256) void xtrans_kernel(float* __restrict__ xhat,
                                                     const float* __restrict__ tmat,
                                                     u16* __restrict__ xhb) {
    __shared__ float4 xs4[16][32];
    __shared__ float Tm[256];
    const int bm = blockIdx.x, t = threadIdx.x;
#pragma unroll
    for (int i = 0; i < 2; ++i) {
        const int f4 = t + i * 256;
        const int j = f4 >> 5, c4 = f4 & 31;
        xs4[j][c4] = ((const float4*)(xhat + (size_t)bm * 2048))[f4];
    }
    Tm[t] = tmat[(size_t)bm * 256 + t];
    __syncthreads();
    const int c4 = t & 31, kk0 = t >> 5;
#pragma unroll
    for (int half = 0; half < 2; ++half) {
        const int kk = kk0 + half * 8;
        float sx = 0.f, sy = 0.f, sz = 0.f, sw = 0.f;
#pragma unroll
        for (int j = 0; j < 16; ++j) {
            const float tv = Tm[kk * 16 + j];
            const float4 xv = xs4[j][c4];
            sx += tv * xv.x; sy += tv * xv.y; sz += tv * xv.z; sw += tv * xv.w;
        }
        const size_t base = (size_t)bm * 2048 + kk * 128 + c4 * 4;
        if (EMIT_BF) {
            ushort4 o;
            o.x = f2bf(sx); o.y = f2bf(sy); o.z = f2bf(sz); o.w = f2bf(sw);
            *(ushort4*)(xhb + base) = o;
        } else {
            float4 o; o.x = sx; o.y = sy; o.z = sz; o.w = sw;
            *(float4*)(xhat + base) = o;
        }
    }
}

// ---------------- final GEMM via bf16 MFMA (R14-proven) --------
__global__ __launch_bounds__(256) void gemm_mfma_final(const u16* __restrict__ XHB,
                                                       const u16* __restrict__ WCBH,
                                                       const float* __restrict__ bno,
                                                       float* __restrict__ out1) {
    __shared__ u16 As[64][72];
    __shared__ u16 Bs[64][72];
    const int t = threadIdx.x;
    const int w = t >> 6, lane = t & 63;
    const int wm = w >> 1, wn = w & 1;
    const int row0 = blockIdx.y * 64, col0 = blockIdx.x * 64;
    const int srow = t >> 2, skq = t & 3;

    f32x4 acc[2][2] = {};

    for (int k0 = 0; k0 < 2048; k0 += 64) {
        __syncthreads();
        const u16* ga = XHB + (size_t)(row0 + srow) * 2048 + k0 + skq * 16;
        const u16* gb = WCBH + (size_t)(col0 + srow) * 2048 + k0 + skq * 16;
        *(us8*)&As[srow][skq * 16 + 0] = *(const us8*)(ga + 0);
        *(us8*)&As[srow][skq * 16 + 8] = *(const us8*)(ga + 8);
        *(us8*)&Bs[srow][skq * 16 + 0] = *(const us8*)(gb + 0);
        *(us8*)&Bs[srow][skq * 16 + 8] = *(const us8*)(gb + 8);
        __syncthreads();
#pragma unroll
        for (int ks = 0; ks < 2; ++ks) {
            const int kb = ks * 32 + (lane >> 4) * 8;
            const bf16x8 a0 = *(const bf16x8*)&As[wm * 32 + (lane & 15)][kb];
            const bf16x8 a1 = *(const bf16x8*)&As[wm * 32 + 16 + (lane & 15)][kb];
            const bf16x8 b0 = *(const bf16x8*)&Bs[wn * 32 + (lane & 15)][kb];
            const bf16x8 b1 = *(const bf16x8*)&Bs[wn * 32 + 16 + (lane & 15)][kb];
            acc[0][0] = __builtin_amdgcn_mfma_f32_16x16x32_bf16(a0, b0, acc[0][0], 0, 0, 0);
            acc[0][1] = __builtin_amdgcn_mfma_f32_16x16x32_bf16(a0, b1, acc[0][1], 0, 0, 0);
            acc[1][0] = __builtin_amdgcn_mfma_f32_16x16x32_bf16(a1, b0, acc[1][0], 0, 0, 0);
            acc[1][1] = __builtin_amdgcn_mfma_f32_16x16x32_bf16(a1, b1, acc[1][1], 0, 0, 0);
        }
    }
#pragma unroll
    for (int mi = 0; mi < 2; ++mi) {
#pragma unroll
        for (int ni = 0; ni < 2; ++ni) {
            const int col = col0 + wn * 32 + ni * 16 + (lane & 15);
            const int rowg = row0 + wm * 32 + mi * 16 + (lane >> 4) * 4;
            const int b = rowg >> 11, m = rowg & 2047;
            float4 v;
            v.x = selu_f(bn_f(acc[mi][ni][0], bno, 256, col));
            v.y = selu_f(bn_f(acc[mi][ni][1], bno, 256, col));
            v.z = selu_f(bn_f(acc[mi][ni][2], bno, 256, col));
            v.w = selu_f(bn_f(acc[mi][ni][3], bno, 256, col));
            *(float4*)(out1 + ((size_t)(b * 256 + col)) * 2048 + m) = v;
        }
    }
}

// ---------------- small prep kernels ----------------
__global__ void transpose_q_kernel(const float* __restrict__ q, float* __restrict__ out0) {
    const int t = blockIdx.x * 256 + threadIdx.x;
    if (t >= 4 * 3 * 2048) return;
    const int b = t / 6144, rem = t % 6144, c = rem >> 11, m = rem & 2047;
    out0[t] = q[((size_t)b * 2048 + m) * 3 + c];
}
__global__ void prep_wt1_kernel(const float* __restrict__ wt1, float* __restrict__ wt1r) {
    const int t = blockIdx.x * 256 + threadIdx.x;
    if (t >= 256 * 48) return;
    const int o = t / 48, rem = t % 48, kk = rem / 3, c = rem % 3;
    wt1r[t] = wt1[o * 48 + c * 16 + kk];
}
__global__ void prep_wc_kernel(const float* __restrict__ wc, float* __restrict__ wcb) {
    const int t = blockIdx.x * 256 + threadIdx.x;
    if (t >= 256 * 2048) return;
    const int o = t >> 11, f = t & 2047, kk = f >> 7, c = f & 127;
    wcb[t] = wc[o * 2048 + c * 16 + kk];
}
__global__ void prep_wcbh_kernel(const float* __restrict__ wcb, u16* __restrict__ wcbh) {
    const int t = blockIdx.x * 256 + threadIdx.x;
    if (t >= 256 * 2048) return;
    wcbh[t] = f2bf(wcb[t]);
}
__global__ void prep_bf16_kernel(const float* __restrict__ src, u16* __restrict__ dst, int n) {
    const int t = blockIdx.x * 256 + threadIdx.x;
    if (t >= n) return;
    dst[t] = f2bf(src[t]);
}

extern "C" void kernel_launch(void* const* d_in, const int* in_sizes, int n_in,
                              void* d_out, int out_size, void* d_ws, size_t ws_size,
                              hipStream_t stream) {
    const float* p    = (const float*)d_in[0];
    const float* x    = (const float*)d_in[1];
    const float* q    = (const float*)d_in[2];
    const float* w1   = (const float*)d_in[3];
    const float* bn1  = (const float*)d_in[4];
    const float* w2   = (const float*)d_in[5];
    const float* bn2  = (const float*)d_in[6];
    const float* wt1  = (const float*)d_in[7];
    const float* bnt1 = (const float*)d_in[8];
    const float* wt2  = (const float*)d_in[9];
    const float* bnt2 = (const float*)d_in[10];
    const float* wt3  = (const float*)d_in[11];
    const float* wc   = (const float*)d_in[12];
    const float* bno  = (const float*)d_in[13];
    float* out = (float*)d_out;

    float* ws   = (float*)d_ws;
    float* WT1R = ws;                         // 12288 floats
    float* WCB  = WT1R + 12288;               // 524288
    int*   IDX  = (int*)(WCB + 524288);       // 131072 ints
    float* PHAT = (float*)(IDX + 131072);     // 393216
    float* BUFA = PHAT + 393216;              // 2097152
    float* BUFB = BUFA + 2097152;             // 2097152
    float* XHAT = BUFB + 2097152;             // 16777216
    u16*   XHB  = (u16*)(XHAT + 16777216);    // 16777216 u16 = 32 MB
    u16*   WCBH = XHB + 16777216;             // 524288 u16 = 1 MB
    u16*   WT2H = WCBH + 524288;              // 65536 u16
    u16*   WT3H = WT2H + 65536;               // 65536 u16
    float* XT   = BUFA;                       // ALIAS: consumed before BUFA written
    u16*   T1H  = (u16*)BUFB;                 // ALIAS: BUFB free in mfma path
    u16*   T2H  = (u16*)BUFB + 2097152;       //   (2x 4MB inside BUFB's 8MB)
    const size_t NEED = (22032384ull + 8388608ull + 262144ull + 65536ull) * 4ull;
    const bool use_mfma = (ws_size >= NEED);

    transpose_q_kernel<<<96, 256, 0, stream>>>(q, out);
    prep_wt1_kernel<<<48, 256, 0, stream>>>(wt1, WT1R);
    prep_wc_kernel<<<2048, 256, 0, stream>>>(wc, WCB);
    if (use_mfma) {
        prep_wcbh_kernel<<<2048, 256, 0, stream>>>(WCB, WCBH);
        prep_bf16_kernel<<<256, 256, 0, stream>>>(wt2, WT2H, 65536);
        prep_bf16_kernel<<<256, 256, 0, stream>>>(wt3, WT3H, 65536);
    }
    transpose_x_kernel<<<dim3(128, 4), 256, 0, stream>>>(x, XT);

    knn_kernel<<<2048, 256, 0, stream>>>(p, q, IDX, PHAT);
    mlp1_kernel<<<8192, 256, 0, stream>>>(XT, w1, bn1, w2, bn2, IDX, PHAT, XHAT);

    if (use_mfma) {
        // t-path: t1 -> bf16, t2/t3 via MFMA (K=256)
        gemm_bt<3><<<dim3(4, 128), 256, 0, stream>>>(PHAT, 48, WT1R, 48, (float*)T1H, 256, 48, bnt1, 256);
        gemm_mfma_t<0><<<dim3(4, 128), 256, 0, stream>>>(T1H, WT2H, 256, bnt2, T2H, nullptr);
        gemm_mfma_t<1><<<dim3(4, 128), 256, 0, stream>>>(T2H, WT3H, 256, nullptr, nullptr, BUFA);
        // y = T @ x_hat -> bf16 XHB
        xtrans_kernel<1><<<8192, 256, 0, stream>>>(XHAT, BUFA, XHB);
        gemm_mfma_final<<<dim3(4, 128), 256, 0, stream>>>(XHB, WCBH, bno, out + 24576);
    } else {
        gemm_bt<1><<<dim3(4, 128), 256, 0, stream>>>(PHAT, 48, WT1R, 48, BUFA, 256, 48, bnt1, 256);
        gemm_bt<1><<<dim3(4, 128), 256, 0, stream>>>(BUFA, 256, wt2, 256, BUFB, 256, 256, bnt2, 256);
        gemm_bt<0><<<dim3(4, 128), 256, 0, stream>>>(BUFB, 256, wt3, 256, BUFA, 256, 256, nullptr, 256);
        xtrans_kernel<0><<<8192, 256, 0, stream>>>(XHAT, BUFA, nullptr);
        gemm_bt<2><<<dim3(4, 128), 256, 0, stream>>>(XHAT, 2048, WCB, 2048, out + 24576, 0, 2048, bno, 256);
    }
}

// Round 23
// 253.645 us; speedup vs baseline: 1.1829x; 1.0546x over previous
//
#include <hip/hip_runtime.h>
#include <hip/hip_bf16.h>
#include <float.h>

#define NPTS 8192
#define KNB  16
#define CINC 64
#define MIDC 64
#define EPSBN 1e-5f

typedef unsigned short u16;
typedef u16   us8   __attribute__((ext_vector_type(8)));
typedef __bf16 bf16x8 __attribute__((ext_vector_type(8)));
typedef float  f32x4  __attribute__((ext_vector_type(4)));

__device__ __forceinline__ float selu_f(float x) {
    const float sc = 1.0507009873554805f;
    const float al = 1.6732632423543772f;
    return x > 0.f ? sc * x : sc * al * expm1f(x);
}
__device__ __forceinline__ float bn_f(float v, const float* __restrict__ bnp, int C, int c) {
    float g = bnp[c], b = bnp[C + c], mu = bnp[2 * C + c], va = bnp[3 * C + c];
    return (v - mu) * (1.0f / sqrtf(va + EPSBN)) * g + b;
}
__device__ __forceinline__ u16 f2bf(float v) {
    __hip_bfloat16 h = __float2bfloat16(v);   // RNE
    return *reinterpret_cast<u16*>(&h);
}

__device__ __forceinline__ unsigned long long wavemin_u64(unsigned long long h) {
#pragma unroll
    for (int s = 32; s >= 1; s >>= 1) {
        const unsigned int ohi = __shfl_xor((unsigned int)(h >> 32), s);
        const unsigned int olo = __shfl_xor((unsigned int)(h & 0xFFFFFFFFu), s);
        const unsigned long long o = ((unsigned long long)ohi << 32) | olo;
        if (o < h) h = o;
    }
    return h;
}

// ---- KNN (R18/R22-PASSING text, FROZEN): two-pass exact threshold ----
__global__ __launch_bounds__(256) void knn_kernel(const float* __restrict__ p,
                                                  const float* __restrict__ q,
                                                  int* __restrict__ idx_out,
                                                  float* __restrict__ phat) {
    const int w = threadIdx.x >> 6, lane = threadIdx.x & 63;
    const int bm = blockIdx.x * 4 + w;
    const int b = bm >> 11;
    const float qx = q[bm * 3 + 0], qy = q[bm * 3 + 1], qz = q[bm * 3 + 2];
    const float qq = __fadd_rn(__fadd_rn(__fmul_rn(qx, qx), __fmul_rn(qy, qy)), __fmul_rn(qz, qz));
    const float* px = p + (size_t)b * 3 * NPTS;
    const float* py = px + NPTS;
    const float* pz = py + NPTS;

    unsigned long long mn = ~0ull;
#pragma unroll 2
    for (int j = 0; j < NPTS / 64; ++j) {
        const int n = lane + j * 64;
        const float ax = px[n], ay = py[n], az = pz[n];
        const float pp = __fadd_rn(__fadd_rn(__fmul_rn(ax, ax), __fmul_rn(ay, ay)), __fmul_rn(az, az));
        const float dt = __fmaf_rn(az, qz, __fmaf_rn(ay, qy, __fmul_rn(ax, qx)));
        const float d2 = __fsub_rn(__fadd_rn(qq, pp), __fmul_rn(2.0f, dt));
        const unsigned int bits = __float_as_uint(d2);
        const unsigned int key = bits ^ ((unsigned int)((int)bits >> 31) | 0x80000000u);
        const unsigned long long nk = ((unsigned long long)key << 32) | (unsigned int)n;
        if (nk < mn) mn = nk;
    }
    unsigned long long T;
    {
        unsigned long long mcur = mn;
        for (int r = 0; r < 16; ++r) {
            const unsigned long long h = wavemin_u64(mcur);
            if (r == 15) T = h;
            if (mcur == h) mcur = ~0ull;
        }
    }

    unsigned long long K[16];
#pragma unroll
    for (int i = 0; i < 16; ++i) K[i] = ~0ull;

#pragma unroll 2
    for (int j = 0; j < NPTS / 64; ++j) {
        const int n = lane + j * 64;
        const float ax = px[n], ay = py[n], az = pz[n];
        const float pp = __fadd_rn(__fadd_rn(__fmul_rn(ax, ax), __fmul_rn(ay, ay)), __fmul_rn(az, az));
        const float dt = __fmaf_rn(az, qz, __fmaf_rn(ay, qy, __fmul_rn(ax, qx)));
        const float d2 = __fsub_rn(__fadd_rn(qq, pp), __fmul_rn(2.0f, dt));
        const unsigned int bits = __float_as_uint(d2);
        const unsigned int key = bits ^ ((unsigned int)((int)bits >> 31) | 0x80000000u);
        const unsigned long long nk = ((unsigned long long)key << 32) | (unsigned int)n;
        if (__any(nk <= T)) {
            if (nk <= T && nk < K[15]) {
                bool c[16];
#pragma unroll
                for (int i = 0; i < 16; ++i) c[i] = nk < K[i];
#pragma unroll
                for (int i = 15; i >= 1; --i) K[i] = c[i] ? (c[i - 1] ? K[i - 1] : nk) : K[i];
                K[0] = c[0] ? nk : K[0];
            }
        }
    }

    unsigned long long win_i = 0, win_p = 0;
    for (int r = 0; r < 16; ++r) {
        const unsigned long long h = wavemin_u64(K[0]);
        const bool own = (K[0] == h);
#pragma unroll
        for (int i = 0; i < 15; ++i) K[i] = own ? K[i + 1] : K[i];
        K[15] = own ? ~0ull : K[15];
        if (r == lane) win_i = h;
        if (lane < 48 && r == (lane / 3)) win_p = h;
    }
    if (lane < 16) idx_out[bm * 16 + lane] = (int)(win_i & 0xFFFFFFFFu);
    if (lane < 48) {
        const int kk = lane / 3, c = lane - kk * 3;
        const int n = (int)(win_p & 0xFFFFFFFFu);
        phat[(size_t)bm * 48 + lane] = p[((size_t)b * 3 + c) * NPTS + n] - q[bm * 3 + c];
    }
}

// ---- fused prep: all independent prep work in ONE dispatch, block-range
//      partitioned; each body is the proven per-kernel text with remapped
//      block index. Ranges:
//      [0,96)       transpose_q        (24576 elems)
//      [96,144)     prep_wt1           (12288 elems)
//      [144,2192)   prep_wc (+wcbh)    (524288 elems)
//      [2192,2704)  transpose_x        (512 tiles: b = l>>7, n0 = (l&127)*64)
//      [2704,2960)  wt2 -> WT2H        (65536 elems)
//      [2960,3216)  wt3 -> WT3H        (65536 elems)
__global__ __launch_bounds__(256) void prep_all_kernel(const float* __restrict__ q,
                                                       const float* __restrict__ wt1,
                                                       const float* __restrict__ wc,
                                                       const float* __restrict__ wt2,
                                                       const float* __restrict__ wt3,
                                                       const float* __restrict__ x,
                                                       float* __restrict__ out0,
                                                       float* __restrict__ wt1r,
                                                       float* __restrict__ wcb,
                                                       u16* __restrict__ wcbh,
                                                       u16* __restrict__ wt2h,
                                                       u16* __restrict__ wt3h,
                                                       float* __restrict__ xT,
                                                       int use_mfma) {
    __shared__ float tile[64][65];
    const int bid = blockIdx.x;
    const int tid = threadIdx.x;
    if (bid < 96) {
        const int t = bid * 256 + tid;
        if (t < 4 * 3 * 2048) {
            const int b = t / 6144, rem = t % 6144, c = rem >> 11, m = rem & 2047;
            out0[t] = q[((size_t)b * 2048 + m) * 3 + c];
        }
    } else if (bid < 144) {
        const int t = (bid - 96) * 256 + tid;
        if (t < 256 * 48) {
            const int o = t / 48, rem = t % 48, kk = rem / 3, c = rem % 3;
            wt1r[t] = wt1[o * 48 + c * 16 + kk];
        }
    } else if (bid < 2192) {
        const int t = (bid - 144) * 256 + tid;
        if (t < 256 * 2048) {
            const int o = t >> 11, f = t & 2047, kk = f >> 7, c = f & 127;
            const float v = wc[o * 2048 + c * 16 + kk];
            wcb[t] = v;
            if (use_mfma) wcbh[t] = f2bf(v);
        }
    } else if (bid < 2704) {
        const int l = bid - 2192;
        const int b = l >> 7;
        const int n0 = (l & 127) * 64;
        const int tn = tid & 63, tq = tid >> 6;
#pragma unroll
        for (int i = 0; i < 16; ++i) {
            const int c = tq * 16 + i;
            tile[c][tn] = x[((size_t)b * 64 + c) * NPTS + n0 + tn];
        }
        __syncthreads();
#pragma unroll
        for (int i = 0; i < 16; ++i) {
            const int n = tq * 16 + i;
            xT[((size_t)b * NPTS + n0 + n) * 64 + tn] = tile[tn][n];
        }
    } else if (bid < 2960) {
        if (use_mfma) {
            const int t = (bid - 2704) * 256 + tid;
            if (t < 65536) wt2h[t] = f2bf(wt2[t]);
        }
    } else {
        if (use_mfma) {
            const int t = (bid - 2960) * 256 + tid;
            if (t < 65536) wt3h[t] = f2bf(wt3[t]);
        }
    }
}

// ---------------- fused gather + mlp1 (R20-passing) ----------------
__global__ __launch_bounds__(256) void mlp1_kernel(const float* __restrict__ xT,
                                                   const float* __restrict__ w1,
                                                   const float* __restrict__ bn1,
                                                   const float* __restrict__ w2,
                                                   const float* __restrict__ bn2,
                                                   const int* __restrict__ idxb,
                                                   const float* __restrict__ phat,
                                                   float* __restrict__ xhat) {
    __shared__ float ph[48];
    __shared__ float h1[16 * 64];
    __shared__ float4 w2s4[16][64];
    __shared__ int idxs[16];
    const int bm = blockIdx.x;
    const int b = bm >> 11;
    const int t = threadIdx.x;
    if (t < 48) ph[t] = phat[(size_t)bm * 48 + t];
    if (t < 16) idxs[t] = idxb[bm * 16 + t];
#pragma unroll
    for (int i = 0; i < 4; ++i) {
        const int fi = t + i * 256;
        const int e = fi >> 4, dq = fi & 15;
        w2s4[dq][e] = ((const float4*)w2)[fi];
    }
    __syncthreads();
#pragma unroll
    for (int i = 0; i < 4; ++i) {
        const int o = t + i * 256;
        const int kk = o >> 6, d = o & 63;
        float s = ph[kk * 3 + 0] * w1[d * 3 + 0] + ph[kk * 3 + 1] * w1[d * 3 + 1] + ph[kk * 3 + 2] * w1[d * 3 + 2];
        h1[kk * 64 + d] = selu_f(bn_f(s, bn1, MIDC, d));
    }
    __syncthreads();
#pragma unroll
    for (int i = 0; i < 4; ++i) {
        const int o = t + i * 256;
        const int kk = o >> 6, e = o & 63;
        const float4* h4 = (const float4*)&h1[kk * 64];
        float s = 0.f;
#pragma unroll
        for (int dq = 0; dq < 16; ++dq) {
            const float4 hv = h4[dq];
            const float4 wv = w2s4[dq][e];
            s += hv.x * wv.x; s += hv.y * wv.y; s += hv.z * wv.z; s += hv.w * wv.w;
        }
        xhat[(size_t)bm * 2048 + kk * 128 + e] = selu_f(bn_f(s, bn2, MIDC, e));
    }
    {
        const int kk = t >> 4, c4 = t & 15;
        const float4 v = *(const float4*)(xT + ((size_t)b * NPTS + idxs[kk]) * 64 + c4 * 4);
        *(float4*)(xhat + (size_t)bm * 2048 + kk * 128 + 64 + c4 * 4) = v;
    }
}

// ---------------- generic tiled fp32 GEMM: C = A[M][K] x B[N][K]^T ----------------
// MODE 0: plain fp32; 1: bn+selu fp32; 2: bn+selu transposed; 3: bn+selu -> bf16 u16
template <int MODE>
__global__ __launch_bounds__(256) void gemm_bt(const float* __restrict__ A, int lda,
                                               const float* __restrict__ B, int ldb,
                                               float* __restrict__ C, int ldc,
                                               int Kd, const float* __restrict__ bnp, int Nc) {
    __shared__ float As[16][68];
    __shared__ float Bs[16][68];
    const int t = threadIdx.x;
    const int tx = t & 15, ty = t >> 4;
    const int row0 = blockIdx.y * 64, col0 = blockIdx.x * 64;
    const int r = t >> 2, q4 = t & 3;
    float acc[4][4] = {};
    for (int k0 = 0; k0 < Kd; k0 += 16) {
        const float4 av = *(const float4*)(A + (size_t)(row0 + r) * lda + k0 + q4 * 4);
        const float4 bv = *(const float4*)(B + (size_t)(col0 + r) * ldb + k0 + q4 * 4);
        As[q4 * 4 + 0][r] = av.x; As[q4 * 4 + 1][r] = av.y;
        As[q4 * 4 + 2][r] = av.z; As[q4 * 4 + 3][r] = av.w;
        Bs[q4 * 4 + 0][r] = bv.x; Bs[q4 * 4 + 1][r] = bv.y;
        Bs[q4 * 4 + 2][r] = bv.z; Bs[q4 * 4 + 3][r] = bv.w;
        __syncthreads();
#pragma unroll
        for (int kk = 0; kk < 16; ++kk) {
            float a0 = As[kk][ty * 4 + 0], a1 = As[kk][ty * 4 + 1];
            float a2 = As[kk][ty * 4 + 2], a3 = As[kk][ty * 4 + 3];
            float b0 = Bs[kk][tx * 4 + 0], b1 = Bs[kk][tx * 4 + 1];
            float b2 = Bs[kk][tx * 4 + 2], b3 = Bs[kk][tx * 4 + 3];
            acc[0][0] += a0 * b0; acc[0][1] += a0 * b1; acc[0][2] += a0 * b2; acc[0][3] += a0 * b3;
            acc[1][0] += a1 * b0; acc[1][1] += a1 * b1; acc[1][2] += a1 * b2; acc[1][3] += a1 * b3;
            acc[2][0] += a2 * b0; acc[2][1] += a2 * b1; acc[2][2] += a2 * b2; acc[2][3] += a2 * b3;
            acc[3][0] += a3 * b0; acc[3][1] += a3 * b1; acc[3][2] += a3 * b2; acc[3][3] += a3 * b3;
        }
        __syncthreads();
    }
#pragma unroll
    for (int i = 0; i < 4; ++i) {
#pragma unroll
        for (int j = 0; j < 4; ++j) {
            const int row = row0 + ty * 4 + i, col = col0 + tx * 4 + j;
            float v = acc[i][j];
            if (MODE >= 1) v = selu_f(bn_f(v, bnp, Nc, col));
            if (MODE == 2) {
                C[(((size_t)(row >> 11)) * Nc + col) * 2048 + (row & 2047)] = v;
            } else if (MODE == 3) {
                ((u16*)C)[(size_t)row * ldc + col] = f2bf(v);
            } else {
                C[(size_t)row * ldc + col] = v;
            }
        }
    }
}

// ---- t-path GEMM via bf16 MFMA (R22-passing) ----
template <int STORE>
__global__ __launch_bounds__(256) void gemm_mfma_t(const u16* __restrict__ A,
                                                   const u16* __restrict__ B,
                                                   int Kd,
                                                   const float* __restrict__ bnp,
                                                   u16* __restrict__ C16,
                                                   float* __restrict__ C32) {
    __shared__ u16 As[64][72];
    __shared__ u16 Bs[64][72];
    const int t = threadIdx.x;
    const int w = t >> 6, lane = t & 63;
    const int wm = w >> 1, wn = w & 1;
    const int row0 = blockIdx.y * 64, col0 = blockIdx.x * 64;
    const int srow = t >> 2, skq = t & 3;

    f32x4 acc[2][2] = {};

    for (int k0 = 0; k0 < Kd; k0 += 64) {
        __syncthreads();
        const u16* ga = A + (size_t)(row0 + srow) * Kd + k0 + skq * 16;
        const u16* gb = B + (size_t)(col0 + srow) * Kd + k0 + skq * 16;
        *(us8*)&As[srow][skq * 16 + 0] = *(const us8*)(ga + 0);
        *(us8*)&As[srow][skq * 16 + 8] = *(const us8*)(ga + 8);
        *(us8*)&Bs[srow][skq * 16 + 0] = *(const us8*)(gb + 0);
        *(us8*)&Bs[srow][skq * 16 + 8] = *(const us8*)(gb + 8);
        __syncthreads();
#pragma unroll
        for (int ks = 0; ks < 2; ++ks) {
            const int kb = ks * 32 + (lane >> 4) * 8;
            const bf16x8 a0 = *(const bf16x8*)&As[wm * 32 + (lane & 15)][kb];
            const bf16x8 a1 = *(const bf16x8*)&As[wm * 32 + 16 + (lane & 15)][kb];
            const bf16x8 b0 = *(const bf16x8*)&Bs[wn * 32 + (lane & 15)][kb];
            const bf16x8 b1 = *(const bf16x8*)&Bs[wn * 32 + 16 + (lane & 15)][kb];
            acc[0][0] = __builtin_amdgcn_mfma_f32_16x16x32_bf16(a0, b0, acc[0][0], 0, 0, 0);
            acc[0][1] = __builtin_amdgcn_mfma_f32_16x16x32_bf16(a0, b1, acc[0][1], 0, 0, 0);
            acc[1][0] = __builtin_amdgcn_mfma_f32_16x16x32_bf16(a1, b0, acc[1][0], 0, 0, 0);
            acc[1][1] = __builtin_amdgcn_mfma_f32_16x16x32_bf16(a1, b1, acc[1][1], 0, 0, 0);
        }
    }
#pragma unroll
    for (int mi = 0; mi < 2; ++mi) {
#pragma unroll
        for (int ni = 0; ni < 2; ++ni) {
            const int col = col0 + wn * 32 + ni * 16 + (lane & 15);
            const int rowg = row0 + wm * 32 + mi * 16 + (lane >> 4) * 4;
#pragma unroll
            for (int r2 = 0; r2 < 4; ++r2) {
                float v = acc[mi][ni][r2];
                if (STORE == 0) {
                    v = selu_f(bn_f(v, bnp, 256, col));
                    C16[(size_t)(rowg + r2) * 256 + col] = f2bf(v);
                } else {
                    C32[(size_t)(rowg + r2) * 256 + col] = v;
                }
            }
        }
    }
}

// ---------------- per-m X-transform (float4 LDS, R20-passing) ----------
template <int EMIT_BF>
__global__ __launch_bounds__(256) void xtrans_kernel(float* __restrict__ xhat,
                                                     const float* __restrict__ tmat,
                                                     u16* __restrict__ xhb) {
    __shared__ float4 xs4[16][32];
    __shared__ float Tm[256];
    const int bm = blockIdx.x, t = threadIdx.x;
#pragma unroll
    for (int i = 0; i < 2; ++i) {
        const int f4 = t + i * 256;
        const int j = f4 >> 5, c4 = f4 & 31;
        xs4[j][c4] = ((const float4*)(xhat + (size_t)bm * 2048))[f4];
    }
    Tm[t] = tmat[(size_t)bm * 256 + t];
    __syncthreads();
    const int c4 = t & 31, kk0 = t >> 5;
#pragma unroll
    for (int half = 0; half < 2; ++half) {
        const int kk = kk0 + half * 8;
        float sx = 0.f, sy = 0.f, sz = 0.f, sw = 0.f;
#pragma unroll
        for (int j = 0; j < 16; ++j) {
            const float tv = Tm[kk * 16 + j];
            const float4 xv = xs4[j][c4];
            sx += tv * xv.x; sy += tv * xv.y; sz += tv * xv.z; sw += tv * xv.w;
        }
        const size_t base = (size_t)bm * 2048 + kk * 128 + c4 * 4;
        if (EMIT_BF) {
            ushort4 o;
            o.x = f2bf(sx); o.y = f2bf(sy); o.z = f2bf(sz); o.w = f2bf(sw);
            *(ushort4*)(xhb + base) = o;
        } else {
            float4 o; o.x = sx; o.y = sy; o.z = sz; o.w = sw;
            *(float4*)(xhat + base) = o;
        }
    }
}

// ---------------- final GEMM via bf16 MFMA (R14-proven) --------
__global__ __launch_bounds__(256) void gemm_mfma_final(const u16* __restrict__ XHB,
                                                       const u16* __restrict__ WCBH,
                                                       const float* __restrict__ bno,
                                                       float* __restrict__ out1) {
    __shared__ u16 As[64][72];
    __shared__ u16 Bs[64][72];
    const int t = threadIdx.x;
    const int w = t >> 6, lane = t & 63;
    const int wm = w >> 1, wn = w & 1;
    const int row0 = blockIdx.y * 64, col0 = blockIdx.x * 64;
    const int srow = t >> 2, skq = t & 3;

    f32x4 acc[2][2] = {};

    for (int k0 = 0; k0 < 2048; k0 += 64) {
        __syncthreads();
        const u16* ga = XHB + (size_t)(row0 + srow) * 2048 + k0 + skq * 16;
        const u16* gb = WCBH + (size_t)(col0 + srow) * 2048 + k0 + skq * 16;
        *(us8*)&As[srow][skq * 16 + 0] = *(const us8*)(ga + 0);
        *(us8*)&As[srow][skq * 16 + 8] = *(const us8*)(ga + 8);
        *(us8*)&Bs[srow][skq * 16 + 0] = *(const us8*)(gb + 0);
        *(us8*)&Bs[srow][skq * 16 + 8] = *(const us8*)(gb + 8);
        __syncthreads();
#pragma unroll
        for (int ks = 0; ks < 2; ++ks) {
            const int kb = ks * 32 + (lane >> 4) * 8;
            const bf16x8 a0 = *(const bf16x8*)&As[wm * 32 + (lane & 15)][kb];
            const bf16x8 a1 = *(const bf16x8*)&As[wm * 32 + 16 + (lane & 15)][kb];
            const bf16x8 b0 = *(const bf16x8*)&Bs[wn * 32 + (lane & 15)][kb];
            const bf16x8 b1 = *(const bf16x8*)&Bs[wn * 32 + 16 + (lane & 15)][kb];
            acc[0][0] = __builtin_amdgcn_mfma_f32_16x16x32_bf16(a0, b0, acc[0][0], 0, 0, 0);
            acc[0][1] = __builtin_amdgcn_mfma_f32_16x16x32_bf16(a0, b1, acc[0][1], 0, 0, 0);
            acc[1][0] = __builtin_amdgcn_mfma_f32_16x16x32_bf16(a1, b0, acc[1][0], 0, 0, 0);
            acc[1][1] = __builtin_amdgcn_mfma_f32_16x16x32_bf16(a1, b1, acc[1][1], 0, 0, 0);
        }
    }
#pragma unroll
    for (int mi = 0; mi < 2; ++mi) {
#pragma unroll
        for (int ni = 0; ni < 2; ++ni) {
            const int col = col0 + wn * 32 + ni * 16 + (lane & 15);
            const int rowg = row0 + wm * 32 + mi * 16 + (lane >> 4) * 4;
            const int b = rowg >> 11, m = rowg & 2047;
            float4 v;
            v.x = selu_f(bn_f(acc[mi][ni][0], bno, 256, col));
            v.y = selu_f(bn_f(acc[mi][ni][1], bno, 256, col));
            v.z = selu_f(bn_f(acc[mi][ni][2], bno, 256, col));
            v.w = selu_f(bn_f(acc[mi][ni][3], bno, 256, col));
            *(float4*)(out1 + ((size_t)(b * 256 + col)) * 2048 + m) = v;
        }
    }
}

extern "C" void kernel_launch(void* const* d_in, const int* in_sizes, int n_in,
                              void* d_out, int out_size, void* d_ws, size_t ws_size,
                              hipStream_t stream) {
    const float* p    = (const float*)d_in[0];
    const float* x    = (const float*)d_in[1];
    const float* q    = (const float*)d_in[2];
    const float* w1   = (const float*)d_in[3];
    const float* bn1  = (const float*)d_in[4];
    const float* w2   = (const float*)d_in[5];
    const float* bn2  = (const float*)d_in[6];
    const float* wt1  = (const float*)d_in[7];
    const float* bnt1 = (const float*)d_in[8];
    const float* wt2  = (const float*)d_in[9];
    const float* bnt2 = (const float*)d_in[10];
    const float* wt3  = (const float*)d_in[11];
    const float* wc   = (const float*)d_in[12];
    const float* bno  = (const float*)d_in[13];
    float* out = (float*)d_out;

    float* ws   = (float*)d_ws;
    float* WT1R = ws;                         // 12288 floats
    float* WCB  = WT1R + 12288;               // 524288
    int*   IDX  = (int*)(WCB + 524288);       // 131072 ints
    float* PHAT = (float*)(IDX + 131072);     // 393216
    float* BUFA = PHAT + 393216;              // 2097152
    float* BUFB = BUFA + 2097152;             // 2097152
    float* XHAT = BUFB + 2097152;             // 16777216
    u16*   XHB  = (u16*)(XHAT + 16777216);    // 16777216 u16 = 32 MB
    u16*   WCBH = XHB + 16777216;             // 524288 u16 = 1 MB
    u16*   WT2H = WCBH + 524288;              // 65536 u16
    u16*   WT3H = WT2H + 65536;               // 65536 u16
    float* XT   = BUFA;                       // ALIAS: consumed before BUFA written
    u16*   T1H  = (u16*)BUFB;                 // ALIAS: BUFB free in mfma path
    u16*   T2H  = (u16*)BUFB + 2097152;
    const size_t NEED = (22032384ull + 8388608ull + 262144ull + 65536ull) * 4ull;
    const bool use_mfma = (ws_size >= NEED);

    prep_all_kernel<<<3216, 256, 0, stream>>>(q, wt1, wc, wt2, wt3, x,
                                              out, WT1R, WCB, WCBH, WT2H, WT3H, XT,
                                              use_mfma ? 1 : 0);

    knn_kernel<<<2048, 256, 0, stream>>>(p, q, IDX, PHAT);
    mlp1_kernel<<<8192, 256, 0, stream>>>(XT, w1, bn1, w2, bn2, IDX, PHAT, XHAT);

    if (use_mfma) {
        gemm_bt<3><<<dim3(4, 128), 256, 0, stream>>>(PHAT, 48, WT1R, 48, (float*)T1H, 256, 48, bnt1, 256);
        gemm_mfma_t<0><<<dim3(4, 128), 256, 0, stream>>>(T1H, WT2H, 256, bnt2, T2H, nullptr);
        gemm_mfma_t<1><<<dim3(4, 128), 256, 0, stream>>>(T2H, WT3H, 256, nullptr, nullptr, BUFA);
        xtrans_kernel<1><<<8192, 256, 0, stream>>>(XHAT, BUFA, XHB);
        gemm_mfma_final<<<dim3(4, 128), 256, 0, stream>>>(XHB, WCBH, bno, out + 24576);
    } else {
        gemm_bt<1><<<dim3(4, 128), 256, 0, stream>>>(PHAT, 48, WT1R, 48, BUFA, 256, 48, bnt1, 256);
        gemm_bt<1><<<dim3(4, 128), 256, 0, stream>>>(BUFA, 256, wt2, 256, BUFB, 256, 256, bnt2, 256);
        gemm_bt<0><<<dim3(4, 128), 256, 0, stream>>>(BUFB, 256, wt3, 256, BUFA, 256, 256, nullptr, 256);
        xtrans_kernel<0><<<8192, 256, 0, stream>>>(XHAT, BUFA, nullptr);
        gemm_bt<2><<<dim3(4, 128), 256, 0, stream>>>(XHAT, 2048, WCB, 2048, out + 24576, 0, 2048, bno, 256);
    }
}